// Round 1
// 144.682 us; speedup vs baseline: 1.0259x; 1.0259x over previous
//
#include <hip/hip_runtime.h>
#include <hip/hip_bf16.h>
#include <hip/hip_fp16.h>

// SumAggregator: out[n, :] = sum_{i<32} emb_table[neighs[n*32 + i], :], DIM=128.
// Phase 1: fp32 table -> fp16 in d_ws (halves gather traffic; 25.6MB ~ L3-resident).
// Phase 2: gather fp16 rows, accumulate fp32.
// R4: gather was LATENCY-bound (VALUBusy 21%, L2-read BW 7.4/34.5 TB/s, 42% L2 miss
// to L3 at ~400-900cy). Full-unroll all 32 row loads into u[32] (64 VGPRs) and issue
// them before accumulating -> ~4x loads-in-flight per wave. 32-bit index math.

constexpr int DIM  = 128;
constexpr int DIM4 = DIM / 4;   // float4 / uint2 per row
constexpr int NB   = 32;

// ---- phase 1: fp32 -> fp16 table conversion (streaming, 32B in / 16B out per thread) ----
__global__ __launch_bounds__(256) void convert_kernel(
    const float4* __restrict__ emb,   // [num_ids*DIM4]
    uint4* __restrict__ emb_h,        // [num_ids*DIM4/2] (8 halves each)
    int n8)                           // num_ids*DIM/8
{
    int i = blockIdx.x * blockDim.x + threadIdx.x;
    int stride = gridDim.x * blockDim.x;
    for (; i < n8; i += stride) {
        float4 a = emb[2 * i];
        float4 b = emb[2 * i + 1];
        __half2 h0 = __floats2half2_rn(a.x, a.y);
        __half2 h1 = __floats2half2_rn(a.z, a.w);
        __half2 h2 = __floats2half2_rn(b.x, b.y);
        __half2 h3 = __floats2half2_rn(b.z, b.w);
        uint4 o;
        o.x = *reinterpret_cast<unsigned int*>(&h0);
        o.y = *reinterpret_cast<unsigned int*>(&h1);
        o.z = *reinterpret_cast<unsigned int*>(&h2);
        o.w = *reinterpret_cast<unsigned int*>(&h3);
        emb_h[i] = o;
    }
}

// ---- phase 2: gather fp16 rows, accumulate fp32 ----
// 32 lanes per node (8B of the 256B row per lane); 2 nodes per wave64.
// All 32 row loads issued up-front (u[32] in registers) for max MLP.
__global__ __launch_bounds__(256) void gather_h_kernel(
    const int* __restrict__ neighs,
    const uint2* __restrict__ emb_h,  // [num_ids][DIM4] 8B chunks
    float4* __restrict__ out,         // [node_count][DIM4]
    int node_count)
{
    int t = blockIdx.x * blockDim.x + threadIdx.x;
    int node = t >> 5;
    int lane = t & 31;
    if (node >= node_count) return;

    int my_idx = neighs[node * NB + lane];   // coalesced 128B per 32-group

    // Issue all 32 row loads before touching any result.
    uint2 u[NB];
#pragma unroll
    for (int i = 0; i < NB; ++i) {
        int id = __shfl(my_idx, i, 32);
        // 32-bit index math: id*32 + lane < 3.2M, fits easily
        unsigned off = (unsigned)id * (unsigned)DIM4 + (unsigned)lane;
        u[i] = emb_h[off];                   // 8B/lane, 256B/row
    }

    float4 acc = make_float4(0.f, 0.f, 0.f, 0.f);
#pragma unroll
    for (int i = 0; i < NB; ++i) {
        __half2 p0 = *reinterpret_cast<__half2*>(&u[i].x);
        __half2 p1 = *reinterpret_cast<__half2*>(&u[i].y);
        float2 f0 = __half22float2(p0);
        float2 f1 = __half22float2(p1);
        acc.x += f0.x; acc.y += f0.y; acc.z += f1.x; acc.w += f1.y;
    }
    out[(size_t)node * DIM4 + lane] = acc;
}

// ---- fp32 fallback (ws too small or nb_count != 32) ----
__global__ __launch_bounds__(256) void gather_f32_kernel(
    const int* __restrict__ neighs,
    const float4* __restrict__ emb,
    float4* __restrict__ out,
    int node_count, int nb_count)
{
    int t = blockIdx.x * blockDim.x + threadIdx.x;
    int node = t >> 5;
    int lane = t & 31;
    if (node >= node_count) return;

    const int* __restrict__ idx = neighs + (size_t)node * nb_count;
    float4 acc = make_float4(0.f, 0.f, 0.f, 0.f);
    for (int i = 0; i < nb_count; ++i) {
        int id = idx[i];
        float4 v = emb[(size_t)id * DIM4 + lane];
        acc.x += v.x; acc.y += v.y; acc.z += v.z; acc.w += v.w;
    }
    out[(size_t)node * DIM4 + lane] = acc;
}

extern "C" void kernel_launch(void* const* d_in, const int* in_sizes, int n_in,
                              void* d_out, int out_size, void* d_ws, size_t ws_size,
                              hipStream_t stream)
{
    const int* neighs = (const int*)d_in[0];
    const float4* emb = (const float4*)d_in[2];
    float4* out = (float4*)d_out;

    const int node_count = out_size / DIM;             // 50000
    const int nb_count   = in_sizes[0] / node_count;   // 32
    const int num_ids    = in_sizes[2] / DIM;          // 100000

    const size_t ws_needed = (size_t)num_ids * DIM * sizeof(__half);  // 25.6 MB

    const int block = 256;

    if (nb_count == NB && ws_size >= ws_needed) {
        // phase 1: convert table to fp16 in workspace
        uint4* emb_h = (uint4*)d_ws;
        const int n8 = num_ids * (DIM / 8);
        const int cgrid = (n8 + block - 1) / block;
        convert_kernel<<<cgrid, block, 0, stream>>>(emb, emb_h, n8);

        // phase 2: fp16 gather (full-unroll MLP)
        const int threads_total = node_count * 32;
        const int grid = (threads_total + block - 1) / block;
        gather_h_kernel<<<grid, block, 0, stream>>>(neighs, (const uint2*)d_ws, out, node_count);
    } else {
        const int threads_total = node_count * 32;
        const int grid = (threads_total + block - 1) / block;
        gather_f32_kernel<<<grid, block, 0, stream>>>(neighs, emb, out, node_count, nb_count);
    }
}